// Round 1
// baseline (216.291 us; speedup 1.0000x reference)
//
#include <hip/hip_runtime.h>

// LearnableLogisticModel: out = sigmoid( sum_k gate_k * (g_k(X) @ w_k) )
// D=64. Monomial decomposition; never materialize features.
// w2: [0:64) squares, [64:2080) cross (triu row-major)
// w3: [0:64) cubes, [64:2080) xi^2*xj, [2080:4096) xi*xj^2, [4096:45760) xi*xj*xk (i<j<k lex)

#define DD 64

__device__ __forceinline__ void compute_gates(const float* __restrict__ alpha,
                                              float& g0, float& g1, float& g2, float& g3) {
    float a0 = alpha[0], a1 = alpha[1], a2 = alpha[2], a3 = alpha[3];
    float m = fmaxf(fmaxf(a0, a1), fmaxf(a2, a3));
    float e0 = __expf(a0 - m), e1 = __expf(a1 - m);
    float e2 = __expf(a2 - m), e3 = __expf(a3 - m);
    float inv = 1.0f / (e0 + e1 + e2 + e3);
    g0 = e0 * inv; g1 = e1 * inv; g2 = e2 * inv; g3 = e3 * inv;
}

// Block: 256 threads = 4 waves. Each block: one 64-sample tile, i-group of 4.
// Wave w handles leading-index i = ig*4 + w for all its pair/triple monomials.
__global__ __launch_bounds__(256) void poly_main(
    const float* __restrict__ X,
    const float* __restrict__ w1,
    const float* __restrict__ w2,
    const float* __restrict__ w3,
    const float* __restrict__ alpha,
    float* __restrict__ ws_acc)
{
    __shared__ float XT[DD][DD + 1];   // transposed tile, +1 pad for write side
    __shared__ float part[256];

    const int tid  = threadIdx.x;
    const int bt   = blockIdx.x;
    const int tile = bt >> 4;          // 128 tiles
    const int ig   = bt & 15;          // 16 i-groups
    const int lane = tid & 63;
    const int wv   = tid >> 6;
    const int i    = __builtin_amdgcn_readfirstlane(ig * 4 + wv);  // wave-uniform

    // stage X tile transposed: global reads coalesced (idx = s*64 + d)
    const float* Xt = X + (size_t)tile * (64 * DD);
    for (int idx = tid; idx < 64 * DD; idx += 256) {
        int s = idx >> 6, d = idx & 63;
        XT[d][s] = Xt[idx];
    }
    __syncthreads();

    float g0, g1, g2, g3;
    compute_gates(alpha, g0, g1, g2, g3);

    // bases for this i
    const int pbase = i * 63 - (i * (i - 1)) / 2;            // triu(i, i+1) offset
    int tbase = 0;
    for (int r = 0; r < i; ++r) tbase += ((63 - r) * (62 - r)) >> 1;  // triple offset

    const float* w2c  = w2 + 64 + pbase;
    const float* w3a  = w3 + 64 + pbase;
    const float* w3b  = w3 + 64 + 2016 + pbase;
    const float* w3tr = w3 + 4096 + tbase;

    const float xi  = XT[i][lane];
    const float xi2 = xi * xi;
    float acc1 = w1[i] * xi;
    float acc2 = w2[i] * xi2;
    float acc3 = w3[i] * (xi2 * xi);

    int p = 0, t = 0;
    for (int j = i + 1; j < 64; ++j) {
        float xj  = XT[j][lane];
        float xij = xi * xj;
        acc2 = fmaf(w2c[p], xij, acc2);
        acc3 = fmaf(w3a[p], xij * xi, acc3);
        acc3 = fmaf(w3b[p], xij * xj, acc3);
        float s = 0.0f;
        for (int k = j + 1; k < 64; ++k, ++t) {
            s = fmaf(w3tr[t], XT[k][lane], s);   // 1 ds_read + 1 fma per monomial
        }
        acc3 = fmaf(xij, s, acc3);
        ++p;
    }

    part[tid] = g1 * acc1 + g2 * acc2 + g3 * acc3;
    __syncthreads();
    if (tid < 64) {
        float v = part[tid] + part[tid + 64] + part[tid + 128] + part[tid + 192];
        atomicAdd(&ws_acc[tile * 64 + tid], v);
    }
}

__global__ __launch_bounds__(256) void poly_finish(
    const float* __restrict__ ws_acc,
    const float* __restrict__ w0,
    const float* __restrict__ alpha,
    float* __restrict__ out, int n_total)
{
    int n = blockIdx.x * blockDim.x + threadIdx.x;
    if (n >= n_total) return;
    float g0, g1, g2, g3;
    compute_gates(alpha, g0, g1, g2, g3);
    float f = ws_acc[n] + g0 * w0[0];
    out[n] = 1.0f / (1.0f + __expf(-f));
}

extern "C" void kernel_launch(void* const* d_in, const int* in_sizes, int n_in,
                              void* d_out, int out_size, void* d_ws, size_t ws_size,
                              hipStream_t stream)
{
    const float* X     = (const float*)d_in[0];
    const float* w0    = (const float*)d_in[1];
    const float* w1    = (const float*)d_in[2];
    const float* w2    = (const float*)d_in[3];
    const float* w3    = (const float*)d_in[4];
    const float* alpha = (const float*)d_in[5];
    float* out = (float*)d_out;
    float* acc = (float*)d_ws;

    const int N = in_sizes[0] / DD;        // 8192 samples
    hipMemsetAsync(acc, 0, (size_t)N * sizeof(float), stream);

    dim3 grid((N / 64) * 16);              // 128 tiles * 16 i-groups = 2048 blocks
    poly_main<<<grid, 256, 0, stream>>>(X, w1, w2, w3, alpha, acc);
    poly_finish<<<(N + 255) / 256, 256, 0, stream>>>(acc, w0, alpha, out, N);
}

// Round 2
// 67.147 us; speedup vs baseline: 3.2211x; 3.2211x over previous
//
#include <hip/hip_runtime.h>
#include <hip/hip_bf16.h>

// out = sigmoid( g0*w0 + g1*(X@w1) + g2*(q(X)@w2) + g3*(c(X)@w3) ), D=64, N=8192
// Cubic via GEMM: monomial {a<=b<=c} w -> W[pair(b,c), a]; f3[n] = sum_p (x_b x_c) * (X@W^T)[n,p]
// pairs p=(j<=k) row-major: 2080 = 130 tiles of 16.

#define DD 64
#define NPAIR 2080
#define NCROSS 2016
#define NW3 45760

typedef __attribute__((ext_vector_type(8))) short short8;
typedef __attribute__((ext_vector_type(4))) short short4_t;
typedef __attribute__((ext_vector_type(4))) float f32x4;

// ws layout (bytes)
#define W_OFF   0u            // bf16 [2080][64]  = 266240 B
#define XB_OFF  266240u       // bf16 [8192][64]  = 1048576 B
#define ACC_OFF 1314816u      // f32  [8192]      = 32768 B
#define T1_OFF  1347584u      // uint [2080] (j<<8|k, j<=k)
#define T2_OFF  1355904u      // uint [2016] (i<<8|j, i<j)

__device__ __forceinline__ int pidx(int a, int b) {   // a<=b
    return a * 64 - (a * (a - 1)) / 2 + (b - a);
}

__device__ __forceinline__ short f2bf(float v) {
    __hip_bfloat16 h = __float2bfloat16(v);
    return (short)__builtin_bit_cast(unsigned short, h);
}

__device__ __forceinline__ void compute_gates(const float* __restrict__ alpha,
                                              float& g0, float& g1, float& g2, float& g3) {
    float a0 = alpha[0], a1 = alpha[1], a2 = alpha[2], a3 = alpha[3];
    float m = fmaxf(fmaxf(a0, a1), fmaxf(a2, a3));
    float e0 = __expf(a0 - m), e1 = __expf(a1 - m);
    float e2 = __expf(a2 - m), e3 = __expf(a3 - m);
    float inv = 1.0f / (e0 + e1 + e2 + e3);
    g0 = e0 * inv; g1 = e1 * inv; g2 = e2 * inv; g3 = e3 * inv;
}

// ---------- prep: zero W + acc, build pair-decode tables ----------
__global__ void prep_kernel(unsigned int* Wz, float* acc, unsigned int* t1,
                            unsigned int* t2, int n_samples) {
    int t = blockIdx.x * blockDim.x + threadIdx.x;
    int stride = gridDim.x * blockDim.x;
    for (int i = t; i < (NPAIR * DD) / 2; i += stride) Wz[i] = 0u;   // bf16 zeros
    for (int i = t; i < n_samples; i += stride) acc[i] = 0.0f;
    for (int p = t; p < NPAIR; p += stride) {
        int j = 0, rem = p;
        while (rem >= 64 - j) { rem -= 64 - j; ++j; }
        t1[p] = ((unsigned)j << 8) | (unsigned)(j + rem);
    }
    for (int p = t; p < NCROSS; p += stride) {
        int i = 0, rem = p;
        while (rem >= 63 - i) { rem -= 63 - i; ++i; }
        t2[p] = ((unsigned)i << 8) | (unsigned)(i + 1 + rem);
    }
}

// ---------- scatter w3 -> W (bf16), convert X -> bf16 ----------
__global__ void scatter_kernel(const float* __restrict__ X,
                               const float* __restrict__ w3,
                               const unsigned int* __restrict__ t2,
                               short* __restrict__ W, short* __restrict__ Xb,
                               int n_x4) {
    int t = blockIdx.x * blockDim.x + threadIdx.x;
    if (t < n_x4) {               // X convert, 4 elems/thread
        float4 v = ((const float4*)X)[t];
        short4_t s;
        s[0] = f2bf(v.x); s[1] = f2bf(v.y); s[2] = f2bf(v.z); s[3] = f2bf(v.w);
        ((short4_t*)Xb)[t] = s;
    }
    if (t < NW3) {
        float v = w3[t];
        int row, col;
        if (t < 64) {                       // x_i^3 -> pair(i,i), col i
            row = pidx(t, t); col = t;
        } else if (t < 64 + NCROSS) {       // x_i^2 x_j (i<j) -> pair(i,j), col i
            unsigned ij = t2[t - 64];
            int i = ij >> 8, j = ij & 255;
            row = pidx(i, j); col = i;
        } else if (t < 64 + 2 * NCROSS) {   // x_i x_j^2 (i<j) -> pair(j,j), col i
            unsigned ij = t2[t - (64 + NCROSS)];
            int i = ij >> 8, j = ij & 255;
            row = pidx(j, j); col = i;
        } else {                            // x_i x_j x_k (i<j<k) -> pair(j,k), col i
            int r = t - (64 + 2 * NCROSS);
            int i = 0;
            while (true) { int cnt = ((63 - i) * (62 - i)) >> 1; if (r < cnt) break; r -= cnt; ++i; }
            int j = i + 1;
            while (r >= 63 - j) { r -= 63 - j; ++j; }
            int k = j + 1 + r;
            row = pidx(j, k); col = i;
        }
        W[row * 64 + col] = f2bf(v);
    }
}

// ---------- main: fused GEMM(X@W^T) * y epilogue + f1/f2 ----------
// block = 256 thr (4 waves), 32 samples, one pair-quarter of the 130 N-tiles.
__global__ __launch_bounds__(256) void poly_mfma(
    const float* __restrict__ X,
    const float* __restrict__ w1,
    const float* __restrict__ w2,
    const float* __restrict__ alpha,
    const short* __restrict__ W,
    const short* __restrict__ Xb,
    const unsigned int* __restrict__ t1,
    const unsigned int* __restrict__ t2,
    float* __restrict__ acc)
{
    __shared__ float xs[32][65];
    __shared__ float red[4][32];

    const int tid = threadIdx.x;
    const int lane = tid & 63, wv = tid >> 6;
    const int quarter = blockIdx.x & 3;
    const int tile = blockIdx.x >> 2;
    const int s0 = tile * 32;

    for (int idx = tid; idx < 32 * 64; idx += 256) {
        xs[idx >> 6][idx & 63] = X[(size_t)s0 * 64 + idx];
    }
    __syncthreads();

    float g0, g1, g2, g3;
    compute_gates(alpha, g0, g1, g2, g3);

    const int arow = lane & 15, akg = lane >> 4;
    // A fragments: row = lane&15 (sample), k = 8*(lane>>4)+e ; held for whole kernel
    short8 a0m0 = *(const short8*)(Xb + (size_t)(s0 + arow) * 64 + 8 * akg);
    short8 a1m0 = *(const short8*)(Xb + (size_t)(s0 + arow) * 64 + 32 + 8 * akg);
    short8 a0m1 = *(const short8*)(Xb + (size_t)(s0 + 16 + arow) * 64 + 8 * akg);
    short8 a1m1 = *(const short8*)(Xb + (size_t)(s0 + 16 + arow) * 64 + 32 + 8 * akg);

    float part0[4] = {0, 0, 0, 0}, part1[4] = {0, 0, 0, 0};

    const int qs = quarter * 33;
    const int qe = (qs + 33 < 130) ? qs + 33 : 130;
    for (int nt = qs + wv; nt < qe; nt += 4) {
        const int p = nt * 16 + arow;             // this lane's pair column
        const unsigned jk = t1[p];
        const int pj = jk >> 8, pk = jk & 255;
        short8 b0 = *(const short8*)(W + (size_t)p * 64 + 8 * akg);
        short8 b1 = *(const short8*)(W + (size_t)p * 64 + 32 + 8 * akg);
        f32x4 c0 = {0, 0, 0, 0}, c1 = {0, 0, 0, 0};
        c0 = __builtin_amdgcn_mfma_f32_16x16x32_bf16(a0m0, b0, c0, 0, 0, 0);
        c0 = __builtin_amdgcn_mfma_f32_16x16x32_bf16(a1m0, b1, c0, 0, 0, 0);
        c1 = __builtin_amdgcn_mfma_f32_16x16x32_bf16(a0m1, b0, c1, 0, 0, 0);
        c1 = __builtin_amdgcn_mfma_f32_16x16x32_bf16(a1m1, b1, c1, 0, 0, 0);
        const int rb = 4 * akg;                   // D row = 4*(lane>>4)+r
        #pragma unroll
        for (int r = 0; r < 4; ++r) {
            float y0 = xs[rb + r][pj] * xs[rb + r][pk];
            part0[r] = fmaf(c0[r], y0, part0[r]);
            float y1 = xs[16 + rb + r][pj] * xs[16 + rb + r][pk];
            part1[r] = fmaf(c1[r], y1, part1[r]);
        }
    }

    // reduce across the 16 pair-columns (lane bits 0..3)
    #pragma unroll
    for (int r = 0; r < 4; ++r) {
        float v0 = part0[r], v1 = part1[r];
        for (int m = 1; m <= 8; m <<= 1) {
            v0 += __shfl_xor(v0, m, 64);
            v1 += __shfl_xor(v1, m, 64);
        }
        part0[r] = v0; part1[r] = v1;
    }
    if ((lane & 15) == 0) {
        const int rb = 4 * (lane >> 4);
        #pragma unroll
        for (int r = 0; r < 4; ++r) {
            red[wv][rb + r] = part0[r];
            red[wv][16 + rb + r] = part1[r];
        }
    }
    __syncthreads();
    if (tid < 32) {
        float s = red[0][tid] + red[1][tid] + red[2][tid] + red[3][tid];
        atomicAdd(&acc[s0 + tid], g3 * s);
    }

    // f1 + f2 in fp32 (quarter-0 blocks only): 8 threads per sample
    if (quarter == 0) {
        const int s = tid >> 3, u = tid & 7;
        const float* xr = xs[s];
        float f1 = 0.0f, f2 = 0.0f;
        for (int i = u; i < 64; i += 8) {
            float xi = xr[i];
            f1 = fmaf(w1[i], xi, f1);
            f2 = fmaf(w2[i], xi * xi, f2);
        }
        for (int p2 = u; p2 < NCROSS; p2 += 8) {
            unsigned ij = t2[p2];
            f2 = fmaf(w2[64 + p2], xr[ij >> 8] * xr[ij & 255], f2);
        }
        float v = g1 * f1 + g2 * f2;
        for (int m = 1; m <= 4; m <<= 1) v += __shfl_xor(v, m, 64);
        if (u == 0) atomicAdd(&acc[s0 + s], v);
    }
}

__global__ __launch_bounds__(256) void finish_kernel(
    const float* __restrict__ acc, const float* __restrict__ w0,
    const float* __restrict__ alpha, float* __restrict__ out, int n)
{
    int i = blockIdx.x * 256 + threadIdx.x;
    if (i >= n) return;
    float g0, g1, g2, g3;
    compute_gates(alpha, g0, g1, g2, g3);
    float f = g0 * w0[0] + acc[i];
    out[i] = 1.0f / (1.0f + __expf(-f));
}

extern "C" void kernel_launch(void* const* d_in, const int* in_sizes, int n_in,
                              void* d_out, int out_size, void* d_ws, size_t ws_size,
                              hipStream_t stream)
{
    const float* X     = (const float*)d_in[0];
    const float* w0    = (const float*)d_in[1];
    const float* w1    = (const float*)d_in[2];
    const float* w2    = (const float*)d_in[3];
    const float* w3    = (const float*)d_in[4];
    const float* alpha = (const float*)d_in[5];
    float* out = (float*)d_out;

    char* ws = (char*)d_ws;
    short* W          = (short*)(ws + W_OFF);
    short* Xb         = (short*)(ws + XB_OFF);
    float* acc        = (float*)(ws + ACC_OFF);
    unsigned int* t1  = (unsigned int*)(ws + T1_OFF);
    unsigned int* t2  = (unsigned int*)(ws + T2_OFF);

    const int N = in_sizes[0] / DD;          // 8192

    prep_kernel<<<64, 256, 0, stream>>>((unsigned int*)W, acc, t1, t2, N);
    scatter_kernel<<<(N * DD / 4 + 255) / 256, 256, 0, stream>>>(X, w3, t2, W, Xb, N * DD / 4);
    poly_mfma<<<(N / 32) * 4, 256, 0, stream>>>(X, w1, w2, alpha, W, Xb, t1, t2, acc);
    finish_kernel<<<(N + 255) / 256, 256, 0, stream>>>(acc, w0, alpha, out, N);
}

// Round 3
// 26.537 us; speedup vs baseline: 8.1507x; 2.5304x over previous
//
#include <hip/hip_runtime.h>
#include <hip/hip_bf16.h>

// out = sigmoid( g0*w0 + g1*(X@w1) + g2*f2 + g3*f3 ), D=64, N=8192
// f3 via GEMM: monomial {a<=b<=c} w -> W[pair(b,c), a]; f3[n] = sum_p y_p * (X@W^T)[n,p], y_p = x_j x_k
// f2 folded into epilogue: part += (g3*S[n,p] + g2*w2eff[p]) * y_p
// W pre-packed in MFMA B-fragment order; X tile transposed in LDS for b128 y-reads.

#define DD 64
#define NPAIR 2080
#define NCROSS 2016
#define NW3 45760
#define NTILES 130

typedef __attribute__((ext_vector_type(8))) short short8;
typedef __attribute__((ext_vector_type(4))) short short4_t;
typedef __attribute__((ext_vector_type(4))) float f32x4;

// ws layout (bytes)
#define W_OFF   0u            // bf16 packed [130][2][64][8] = 266240
#define XB_OFF  266240u       // bf16 [8192][64]             = 1048576
#define ACC_OFF 1314816u      // f32  [8192]                 = 32768
#define E_OFF   1347584u      // float2 {g2*w2eff, jk} [2080] = 16640
#define T2_OFF  1364224u      // uint [2016] (i<<8|j, i<j)    = 8064
#define G_OFF   1372288u      // float4 {g0*w0, g1, g2, g3}   = 16

__device__ __forceinline__ int pidx(int a, int b) { return a * 64 - (a * (a - 1)) / 2 + (b - a); }

// packed short-index of element (pair row, k) in MFMA B-frag order
__device__ __forceinline__ int widx(int row, int k) {
    return ((row >> 4) << 10) + ((k >> 5) << 9) + (((row & 15) + (((k >> 3) & 3) << 4)) << 3) + (k & 7);
}

__device__ __forceinline__ short f2bf(float v) {
    __hip_bfloat16 h = __float2bfloat16(v);
    return (short)__builtin_bit_cast(unsigned short, h);
}

__device__ __forceinline__ void compute_gates(const float* __restrict__ alpha,
                                              float& g0, float& g1, float& g2, float& g3) {
    float a0 = alpha[0], a1 = alpha[1], a2 = alpha[2], a3 = alpha[3];
    float m = fmaxf(fmaxf(a0, a1), fmaxf(a2, a3));
    float e0 = __expf(a0 - m), e1 = __expf(a1 - m);
    float e2 = __expf(a2 - m), e3 = __expf(a3 - m);
    float inv = 1.0f / (e0 + e1 + e2 + e3);
    g0 = e0 * inv; g1 = e1 * inv; g2 = e2 * inv; g3 = e3 * inv;
}

// ---------- prep: zero W/acc, build tables, gates ----------
__global__ void prep_kernel(unsigned int* Wz, float* acc, float2* et,
                            unsigned int* t2, float4* gates,
                            const float* __restrict__ alpha,
                            const float* __restrict__ w0,
                            const float* __restrict__ w2, int n_samples) {
    int t = blockIdx.x * blockDim.x + threadIdx.x;
    int stride = gridDim.x * blockDim.x;
    float g0, g1, g2, g3;
    compute_gates(alpha, g0, g1, g2, g3);
    if (t == 0) { float4 g; g.x = g0 * w0[0]; g.y = g1; g.z = g2; g.w = g3; *gates = g; }
    for (int i = t; i < (NPAIR * DD) / 2; i += stride) Wz[i] = 0u;
    for (int i = t; i < n_samples; i += stride) acc[i] = 0.0f;
    for (int p = t; p < NPAIR; p += stride) {          // pair (j<=k) table + bias
        int j = 0, rem = p;
        while (rem >= 64 - j) { rem -= 64 - j; ++j; }
        int k = j + rem;
        float w2e = (j == k) ? w2[j] : w2[64 + 63 * j - (j * (j - 1)) / 2 + (k - j - 1)];
        float2 e; e.x = g2 * w2e;
        e.y = __uint_as_float(((unsigned)j << 8) | (unsigned)k);
        et[p] = e;
    }
    for (int p = t; p < NCROSS; p += stride) {
        int i = 0, rem = p;
        while (rem >= 63 - i) { rem -= 63 - i; ++i; }
        t2[p] = ((unsigned)i << 8) | (unsigned)(i + 1 + rem);
    }
}

// ---------- scatter w3 -> packed W (bf16), X -> bf16 ----------
__global__ void scatter_kernel(const float* __restrict__ X,
                               const float* __restrict__ w3,
                               const unsigned int* __restrict__ t2,
                               short* __restrict__ Wp, short* __restrict__ Xb,
                               int n_x4) {
    int t = blockIdx.x * blockDim.x + threadIdx.x;
    if (t < n_x4) {
        float4 v = ((const float4*)X)[t];
        short4_t s;
        s[0] = f2bf(v.x); s[1] = f2bf(v.y); s[2] = f2bf(v.z); s[3] = f2bf(v.w);
        ((short4_t*)Xb)[t] = s;
    }
    if (t < NW3) {
        float v = w3[t];
        int row, col;
        if (t < 64) {                       // x_i^3 -> pair(i,i), col i
            row = pidx(t, t); col = t;
        } else if (t < 64 + NCROSS) {       // x_i^2 x_j (i<j) -> pair(i,j), col i
            unsigned ij = t2[t - 64];
            int i = ij >> 8, j = ij & 255;
            row = pidx(i, j); col = i;
        } else if (t < 64 + 2 * NCROSS) {   // x_i x_j^2 (i<j) -> pair(j,j), col i
            unsigned ij = t2[t - (64 + NCROSS)];
            int i = ij >> 8, j = ij & 255;
            row = pidx(j, j); col = i;
        } else {                            // x_i x_j x_k (i<j<k) -> pair(j,k), col i
            int r = t - (64 + 2 * NCROSS);
            int i = 0;
            while (true) { int cnt = ((63 - i) * (62 - i)) >> 1; if (r < cnt) break; r -= cnt; ++i; }
            int j = i + 1;
            while (r >= 63 - j) { r -= 63 - j; ++j; }
            int k = j + 1 + r;
            row = pidx(j, k); col = i;
        }
        Wp[widx(row, col)] = f2bf(v);
    }
}

// ---------- main: fused GEMM(X@W^T) epilogue ----------
// block = 256 thr (4 waves), 32 samples, one pair-quarter of 130 N-tiles.
__global__ __launch_bounds__(256) void poly_mfma(
    const float* __restrict__ X,
    const float* __restrict__ w1,
    const short* __restrict__ Wp,
    const short* __restrict__ Xb,
    const float2* __restrict__ et,
    const float4* __restrict__ gates,
    float* __restrict__ acc)
{
    __shared__ float xs[DD][36];     // transposed tile: xs[dim][sample]
    __shared__ float red[4][32];

    const int tid = threadIdx.x;
    const int lane = tid & 63, wv = tid >> 6;
    const int quarter = blockIdx.x & 3;
    const int tile = blockIdx.x >> 2;
    const int s0 = tile * 32;

    for (int idx = tid; idx < 32 * 64; idx += 256) {
        xs[idx & 63][idx >> 6] = X[(size_t)s0 * 64 + idx];
    }
    __syncthreads();

    const float4 g = *gates;
    const float g3 = g.w;

    const int arow = lane & 15, akg = lane >> 4;
    short8 a0m0 = *(const short8*)(Xb + (size_t)(s0 + arow) * 64 + 8 * akg);
    short8 a1m0 = *(const short8*)(Xb + (size_t)(s0 + arow) * 64 + 32 + 8 * akg);
    short8 a0m1 = *(const short8*)(Xb + (size_t)(s0 + 16 + arow) * 64 + 8 * akg);
    short8 a1m1 = *(const short8*)(Xb + (size_t)(s0 + 16 + arow) * 64 + 32 + 8 * akg);

    float part0[4] = {0, 0, 0, 0}, part1[4] = {0, 0, 0, 0};

    // quarter 0: 31 tiles (it also does f1); quarters 1-3: 33 tiles
    const int qs = quarter ? 31 + 33 * (quarter - 1) : 0;
    const int qe = quarter ? qs + 33 : 31;

    int nt = qs + wv;
    short8 b0, b1; float2 e;
    if (nt < qe) {
        const short* wb = Wp + nt * 1024 + lane * 8;
        b0 = *(const short8*)wb;
        b1 = *(const short8*)(wb + 512);
        e = et[nt * 16 + arow];
    }
    while (nt < qe) {
        const int nn = nt + 4;
        short8 nb0, nb1; float2 ne;
        if (nn < qe) {                       // prefetch next iteration
            const short* wb = Wp + nn * 1024 + lane * 8;
            nb0 = *(const short8*)wb;
            nb1 = *(const short8*)(wb + 512);
            ne = et[nn * 16 + arow];
        }
        f32x4 c0 = {0, 0, 0, 0}, c1 = {0, 0, 0, 0};
        c0 = __builtin_amdgcn_mfma_f32_16x16x32_bf16(a0m0, b0, c0, 0, 0, 0);
        c0 = __builtin_amdgcn_mfma_f32_16x16x32_bf16(a1m0, b1, c0, 0, 0, 0);
        c1 = __builtin_amdgcn_mfma_f32_16x16x32_bf16(a0m1, b0, c1, 0, 0, 0);
        c1 = __builtin_amdgcn_mfma_f32_16x16x32_bf16(a1m1, b1, c1, 0, 0, 0);

        const unsigned jk = __float_as_uint(e.y);
        const int pj = jk >> 8, pk = jk & 255;
        const float bp = e.x;
        const f32x4 xj0 = *(const f32x4*)&xs[pj][4 * akg];
        const f32x4 xk0 = *(const f32x4*)&xs[pk][4 * akg];
        const f32x4 xj1 = *(const f32x4*)&xs[pj][16 + 4 * akg];
        const f32x4 xk1 = *(const f32x4*)&xs[pk][16 + 4 * akg];
        #pragma unroll
        for (int r = 0; r < 4; ++r) {
            float t0 = fmaf(g3, c0[r], bp);
            part0[r] = fmaf(t0, xj0[r] * xk0[r], part0[r]);
            float t1 = fmaf(g3, c1[r], bp);
            part1[r] = fmaf(t1, xj1[r] * xk1[r], part1[r]);
        }
        b0 = nb0; b1 = nb1; e = ne; nt = nn;
    }

    #pragma unroll
    for (int r = 0; r < 4; ++r) {
        float v0 = part0[r], v1 = part1[r];
        for (int m = 1; m <= 8; m <<= 1) {
            v0 += __shfl_xor(v0, m, 64);
            v1 += __shfl_xor(v1, m, 64);
        }
        part0[r] = v0; part1[r] = v1;
    }
    if ((lane & 15) == 0) {
        const int rb = 4 * (lane >> 4);
        #pragma unroll
        for (int r = 0; r < 4; ++r) {
            red[wv][rb + r] = part0[r];
            red[wv][16 + rb + r] = part1[r];
        }
    }
    __syncthreads();
    if (tid < 32) {
        float s = red[0][tid] + red[1][tid] + red[2][tid] + red[3][tid];
        atomicAdd(&acc[s0 + tid], s);
    }

    // f1 (linear term), quarter-0 blocks: 8 threads/sample, 8 iters
    if (quarter == 0) {
        const int s = tid >> 3, u = tid & 7;
        float f1 = 0.0f;
        #pragma unroll
        for (int i = u; i < 64; i += 8) f1 = fmaf(w1[i], xs[i][s], f1);
        float v = g.y * f1;
        for (int m = 1; m <= 4; m <<= 1) v += __shfl_xor(v, m, 64);
        if (u == 0) atomicAdd(&acc[s0 + s], v);
    }
}

__global__ __launch_bounds__(256) void finish_kernel(
    const float* __restrict__ acc, const float4* __restrict__ gates,
    float* __restrict__ out, int n)
{
    int i = blockIdx.x * 256 + threadIdx.x;
    if (i >= n) return;
    float f = (*gates).x + acc[i];
    out[i] = 1.0f / (1.0f + __expf(-f));
}

extern "C" void kernel_launch(void* const* d_in, const int* in_sizes, int n_in,
                              void* d_out, int out_size, void* d_ws, size_t ws_size,
                              hipStream_t stream)
{
    const float* X     = (const float*)d_in[0];
    const float* w0    = (const float*)d_in[1];
    const float* w1    = (const float*)d_in[2];
    const float* w2    = (const float*)d_in[3];
    const float* w3    = (const float*)d_in[4];
    const float* alpha = (const float*)d_in[5];
    float* out = (float*)d_out;

    char* ws = (char*)d_ws;
    short* Wp        = (short*)(ws + W_OFF);
    short* Xb        = (short*)(ws + XB_OFF);
    float* acc       = (float*)(ws + ACC_OFF);
    float2* et       = (float2*)(ws + E_OFF);
    unsigned int* t2 = (unsigned int*)(ws + T2_OFF);
    float4* gates    = (float4*)(ws + G_OFF);

    const int N = in_sizes[0] / DD;          // 8192

    prep_kernel<<<64, 256, 0, stream>>>((unsigned int*)Wp, acc, et, t2, gates, alpha, w0, w2, N);
    scatter_kernel<<<(N * DD / 4 + 255) / 256, 256, 0, stream>>>(X, w3, t2, Wp, Xb, N * DD / 4);
    poly_mfma<<<(N / 32) * 4, 256, 0, stream>>>(X, w1, Wp, Xb, et, gates, acc);
    finish_kernel<<<(N + 255) / 256, 256, 0, stream>>>(acc, gates, out, N);
}

// Round 4
// 21.410 us; speedup vs baseline: 10.1022x; 1.2394x over previous
//
#include <hip/hip_runtime.h>
#include <hip/hip_bf16.h>

// out = sigmoid( g0*w0 + g1*(X@w1) + g2*f2 + g3*f3 ), D=64, N=8192
// f3 via GEMM: monomial {a<=b<=c} w -> W[pair(b,c), a]; f3[n] = sum_p y_p * (X@W^T)[n,p], y_p = x_j x_k
// f2 folded into epilogue: part += (g3*S[n,p] + g2*w2eff[p]) * y_p
// Two kernels: build (gather-form packed W + pair table), poly (fused GEMM + epilogue + f1 + sigmoid).

#define DD 64
#define NPAIR 2080
#define NTILES 130

typedef __attribute__((ext_vector_type(8))) short short8;
typedef __attribute__((ext_vector_type(4))) float f32x4;

// ws layout (bytes)
#define W_OFF  0u         // bf16 packed [130][2][64][8] = 266240
#define E_OFF  266240u    // float2 {g2*w2eff, jk} [2080] = 16640

__device__ __forceinline__ short f2bf(float v) {
    __hip_bfloat16 h = __float2bfloat16(v);
    return (short)__builtin_bit_cast(unsigned short, h);
}

__device__ __forceinline__ void compute_gates(const float* __restrict__ alpha,
                                              float& g0, float& g1, float& g2, float& g3) {
    float a0 = alpha[0], a1 = alpha[1], a2 = alpha[2], a3 = alpha[3];
    float m = fmaxf(fmaxf(a0, a1), fmaxf(a2, a3));
    float e0 = __expf(a0 - m), e1 = __expf(a1 - m);
    float e2 = __expf(a2 - m), e3 = __expf(a3 - m);
    float inv = 1.0f / (e0 + e1 + e2 + e3);
    g0 = e0 * inv; g1 = e1 * inv; g2 = e2 * inv; g3 = e3 * inv;
}

// ---------- build: gather-form packed W (no zero pass) + pair table ----------
// 16640 threads; thread t writes packed shorts [8t, 8t+8) with one b128 store.
// Packed layout: idx = (row>>4)*1024 + (k>>5)*512 + ((row&15) + 16*((k>>3)&3))*8 + (k&7)
__global__ __launch_bounds__(256) void build_kernel(
    const float* __restrict__ w2, const float* __restrict__ w3,
    const float* __restrict__ alpha, short* __restrict__ Wp, float2* __restrict__ et)
{
    const int t = blockIdx.x * 256 + threadIdx.x;     // 0..16639
    const int pk = t * 8;
    const int nt = pk >> 10;
    const int rem = pk & 1023;
    const int half = rem >> 9;
    const int fl = (rem & 511) >> 3;                   // fragment lane 0..63
    const int arow = fl & 15, akg = fl >> 4;
    const int row = nt * 16 + arow;                    // pair row 0..2079
    const int kb = half * 32 + akg * 8;                // first col of the 8

    // decode pair row -> (j<=k)
    int j = 0, r2 = row;
    while (r2 >= 64 - j) { r2 -= 64 - j; ++j; }
    const int k = j + r2;

    short8 v;
    #pragma unroll
    for (int e = 0; e < 8; ++e) {
        const int a = kb + e;                          // monomial smallest index
        float w = 0.0f;
        if (a <= j) {
            if (a == j) {
                w = (j == k) ? w3[j]                                   // x_j^3
                             : w3[64 + 63 * j - (j * (j - 1)) / 2 + (k - j - 1)]; // x_j^2 x_k
            } else if (j == k) {                                       // x_a x_j^2
                w = w3[64 + 2016 + 63 * a - (a * (a - 1)) / 2 + (j - a - 1)];
            } else {                                                   // x_a x_j x_k, a<j<k
                const int tb = 41664 - ((64 - a) * (63 - a) * (62 - a)) / 6;
                const int po = ((62 - a + 64 - j) * (j - a - 1)) / 2 + (k - j - 1);
                w = w3[4096 + tb + po];
            }
        }
        v[e] = f2bf(w);
    }
    *(short8*)(Wp + pk) = v;

    if (half == 0 && akg == 0) {                       // exactly one thread per pair row
        float g0, g1, g2, g3;
        compute_gates(alpha, g0, g1, g2, g3);
        float w2e = (j == k) ? w2[j] : w2[64 + 63 * j - (j * (j - 1)) / 2 + (k - j - 1)];
        float2 ev;
        ev.x = g2 * w2e;
        ev.y = __uint_as_float(((unsigned)j << 8) | (unsigned)k);
        et[row] = ev;
    }
}

// ---------- poly: fused GEMM(X@W^T) epilogue + f1 + sigmoid, self-contained ----------
// 256 blocks x 512 thr (8 waves); block owns 32 samples; wave wv walks tiles wv, wv+8, ...
__global__ __launch_bounds__(512) void poly_mfma(
    const float* __restrict__ X,
    const float* __restrict__ w0,
    const float* __restrict__ w1,
    const float* __restrict__ alpha,
    const short* __restrict__ Wp,
    const float2* __restrict__ et,
    float* __restrict__ out)
{
    __shared__ float xs[DD][36];     // transposed tile: xs[dim][sample]
    __shared__ float red[8][32];
    __shared__ float f1s[32];

    const int tid = threadIdx.x;
    const int lane = tid & 63, wv = tid >> 6;
    const int s0 = blockIdx.x * 32;

    for (int idx = tid; idx < 32 * 64; idx += 512) {
        xs[idx & 63][idx >> 6] = X[(size_t)s0 * 64 + idx];
    }

    float g0, g1, g2, g3;
    compute_gates(alpha, g0, g1, g2, g3);

    // A fragments straight from global X (L2-warm), converted in-register
    const int arow = lane & 15, akg = lane >> 4;
    const float* xr0 = X + (size_t)(s0 + arow) * 64 + 8 * akg;
    const float* xr1 = X + (size_t)(s0 + 16 + arow) * 64 + 8 * akg;
    short8 a0m0, a1m0, a0m1, a1m1;
    #pragma unroll
    for (int e = 0; e < 4; ++e) {
        f32x4 v00 = *(const f32x4*)(xr0 + 0);  (void)v00;
    }
    {
        f32x4 p0 = *(const f32x4*)(xr0);
        f32x4 p1 = *(const f32x4*)(xr0 + 4);
        f32x4 q0 = *(const f32x4*)(xr0 + 32);
        f32x4 q1 = *(const f32x4*)(xr0 + 36);
        f32x4 r0 = *(const f32x4*)(xr1);
        f32x4 r1 = *(const f32x4*)(xr1 + 4);
        f32x4 s0v = *(const f32x4*)(xr1 + 32);
        f32x4 s1v = *(const f32x4*)(xr1 + 36);
        #pragma unroll
        for (int e = 0; e < 4; ++e) {
            a0m0[e] = f2bf(p0[e]); a0m0[4 + e] = f2bf(p1[e]);
            a1m0[e] = f2bf(q0[e]); a1m0[4 + e] = f2bf(q1[e]);
            a0m1[e] = f2bf(r0[e]); a0m1[4 + e] = f2bf(r1[e]);
            a1m1[e] = f2bf(s0v[e]); a1m1[4 + e] = f2bf(s1v[e]);
        }
    }

    __syncthreads();

    float part0[4] = {0, 0, 0, 0}, part1[4] = {0, 0, 0, 0};

    int nt = wv;
    short8 b0, b1; float2 e;
    if (nt < NTILES) {
        const short* wb = Wp + nt * 1024 + lane * 8;
        b0 = *(const short8*)wb;
        b1 = *(const short8*)(wb + 512);
        e = et[nt * 16 + arow];
    }
    while (nt < NTILES) {
        const int nn = nt + 8;
        short8 nb0, nb1; float2 ne;
        if (nn < NTILES) {
            const short* wb = Wp + nn * 1024 + lane * 8;
            nb0 = *(const short8*)wb;
            nb1 = *(const short8*)(wb + 512);
            ne = et[nn * 16 + arow];
        }
        f32x4 c0 = {0, 0, 0, 0}, c1 = {0, 0, 0, 0};
        c0 = __builtin_amdgcn_mfma_f32_16x16x32_bf16(a0m0, b0, c0, 0, 0, 0);
        c0 = __builtin_amdgcn_mfma_f32_16x16x32_bf16(a1m0, b1, c0, 0, 0, 0);
        c1 = __builtin_amdgcn_mfma_f32_16x16x32_bf16(a0m1, b0, c1, 0, 0, 0);
        c1 = __builtin_amdgcn_mfma_f32_16x16x32_bf16(a1m1, b1, c1, 0, 0, 0);

        const unsigned jk = __float_as_uint(e.y);
        const int pj = jk >> 8, pk = jk & 255;
        const float bp = e.x;
        const f32x4 xj0 = *(const f32x4*)&xs[pj][4 * akg];
        const f32x4 xk0 = *(const f32x4*)&xs[pk][4 * akg];
        const f32x4 xj1 = *(const f32x4*)&xs[pj][16 + 4 * akg];
        const f32x4 xk1 = *(const f32x4*)&xs[pk][16 + 4 * akg];
        #pragma unroll
        for (int r = 0; r < 4; ++r) {
            float t0 = fmaf(g3, c0[r], bp);
            part0[r] = fmaf(t0, xj0[r] * xk0[r], part0[r]);
            float t1 = fmaf(g3, c1[r], bp);
            part1[r] = fmaf(t1, xj1[r] * xk1[r], part1[r]);
        }
        b0 = nb0; b1 = nb1; e = ne; nt = nn;
    }

    // reduce across the 16 pair-columns (lane bits 0..3)
    #pragma unroll
    for (int r = 0; r < 4; ++r) {
        float v0 = part0[r], v1 = part1[r];
        for (int m = 1; m <= 8; m <<= 1) {
            v0 += __shfl_xor(v0, m, 64);
            v1 += __shfl_xor(v1, m, 64);
        }
        part0[r] = v0; part1[r] = v1;
    }
    if ((lane & 15) == 0) {
        const int rb = 4 * (lane >> 4);
        #pragma unroll
        for (int r = 0; r < 4; ++r) {
            red[wv][rb + r] = part0[r];
            red[wv][16 + rb + r] = part1[r];
        }
    }

    // f1 (linear term): 16 threads per sample, 4 iters each
    {
        const int s = tid >> 4, u = tid & 15;
        float f1 = 0.0f;
        #pragma unroll
        for (int i = 0; i < 4; ++i) f1 = fmaf(w1[u + 16 * i], xs[u + 16 * i][s], f1);
        for (int m = 1; m <= 8; m <<= 1) f1 += __shfl_xor(f1, m, 64);
        if (u == 0) f1s[s] = f1;
    }
    __syncthreads();

    if (tid < 32) {
        float s = red[0][tid] + red[1][tid] + red[2][tid] + red[3][tid]
                + red[4][tid] + red[5][tid] + red[6][tid] + red[7][tid];
        float f = fmaf(g0, w0[0], fmaf(g1, f1s[tid], s));
        out[s0 + tid] = 1.0f / (1.0f + __expf(-f));
    }
}

extern "C" void kernel_launch(void* const* d_in, const int* in_sizes, int n_in,
                              void* d_out, int out_size, void* d_ws, size_t ws_size,
                              hipStream_t stream)
{
    const float* X     = (const float*)d_in[0];
    const float* w0    = (const float*)d_in[1];
    const float* w1    = (const float*)d_in[2];
    const float* w2    = (const float*)d_in[3];
    const float* w3    = (const float*)d_in[4];
    const float* alpha = (const float*)d_in[5];
    float* out = (float*)d_out;

    char* ws = (char*)d_ws;
    short* Wp  = (short*)(ws + W_OFF);
    float2* et = (float2*)(ws + E_OFF);

    const int N = in_sizes[0] / DD;          // 8192

    build_kernel<<<65, 256, 0, stream>>>(w2, w3, alpha, Wp, et);   // 16640 threads
    poly_mfma<<<N / 32, 512, 0, stream>>>(X, w0, w1, alpha, Wp, et, out);
}

// Round 5
// 20.655 us; speedup vs baseline: 10.4716x; 1.0366x over previous
//
#include <hip/hip_runtime.h>
#include <hip/hip_bf16.h>

// out = sigmoid( g0*w0 + g1*(X@w1) + g2*f2 + g3*f3 ), D=64, N=8192
// f3 via GEMM: monomial {a<=b<=c} w -> W[pair(b,c), a]; f3[n] = sum_p y_p * (X@W^T)[n,p], y_p = x_j x_k
// f2 folded into epilogue: part += (g3*S[n,p] + g2*w2eff[p]) * y_p
// R5: 16-wave blocks (4 waves/SIMD), branchless 2-deep B prefetch w/ zero-padded tile 130.

#define DD 64
#define NPAIR 2080
#define NTILES 130
#define PTILES 131   // +1 zero dummy tile for branchless prefetch

typedef __attribute__((ext_vector_type(8))) short short8;
typedef __attribute__((ext_vector_type(4))) float f32x4;

// ws layout (bytes)
#define W_OFF  0u         // bf16 packed [131][2][64][8] = 268288
#define E_OFF  268288u    // float2 {g2*w2eff, jk} [131*16] = 16768

__device__ __forceinline__ short f2bf(float v) {
    __hip_bfloat16 h = __float2bfloat16(v);
    return (short)__builtin_bit_cast(unsigned short, h);
}

__device__ __forceinline__ void compute_gates(const float* __restrict__ alpha,
                                              float& g0, float& g1, float& g2, float& g3) {
    float a0 = alpha[0], a1 = alpha[1], a2 = alpha[2], a3 = alpha[3];
    float m = fmaxf(fmaxf(a0, a1), fmaxf(a2, a3));
    float e0 = __expf(a0 - m), e1 = __expf(a1 - m);
    float e2 = __expf(a2 - m), e3 = __expf(a3 - m);
    float inv = 1.0f / (e0 + e1 + e2 + e3);
    g0 = e0 * inv; g1 = e1 * inv; g2 = e2 * inv; g3 = e3 * inv;
}

// ---------- build: gather-form packed W (no zero pass) + pair table ----------
// thread t writes packed shorts [8t, 8t+8) with one b128 store. 131*128 = 16768 threads.
// Packed layout: idx = (row>>4)*1024 + (k>>5)*512 + ((row&15) + 16*((k>>3)&3))*8 + (k&7)
__global__ __launch_bounds__(256) void build_kernel(
    const float* __restrict__ w2, const float* __restrict__ w3,
    const float* __restrict__ alpha, short* __restrict__ Wp, float2* __restrict__ et)
{
    const int t = blockIdx.x * 256 + threadIdx.x;
    if (t >= PTILES * 128) return;
    const int pk = t * 8;
    const int nt = pk >> 10;
    const int rem = pk & 1023;
    const int half = rem >> 9;
    const int fl = (rem & 511) >> 3;                   // fragment lane 0..63
    const int arow = fl & 15, akg = fl >> 4;
    const int row = nt * 16 + arow;                    // pair row 0..2095
    const int kb = half * 32 + akg * 8;                // first col of the 8

    if (row >= NPAIR) {                                // zero dummy tile
        short8 z = {0, 0, 0, 0, 0, 0, 0, 0};
        *(short8*)(Wp + pk) = z;
        if (half == 0 && akg == 0) { float2 zv; zv.x = 0.0f; zv.y = 0.0f; et[row] = zv; }
        return;
    }

    // decode pair row -> (j<=k)
    int j = 0, r2 = row;
    while (r2 >= 64 - j) { r2 -= 64 - j; ++j; }
    const int k = j + r2;

    short8 v;
    #pragma unroll
    for (int e = 0; e < 8; ++e) {
        const int a = kb + e;                          // monomial smallest index
        float w = 0.0f;
        if (a <= j) {
            if (a == j) {
                w = (j == k) ? w3[j]                                   // x_j^3
                             : w3[64 + 63 * j - (j * (j - 1)) / 2 + (k - j - 1)]; // x_j^2 x_k
            } else if (j == k) {                                       // x_a x_j^2
                w = w3[64 + 2016 + 63 * a - (a * (a - 1)) / 2 + (j - a - 1)];
            } else {                                                   // x_a x_j x_k, a<j<k
                const int tb = 41664 - ((64 - a) * (63 - a) * (62 - a)) / 6;
                const int po = ((62 - a + 64 - j) * (j - a - 1)) / 2 + (k - j - 1);
                w = w3[4096 + tb + po];
            }
        }
        v[e] = f2bf(w);
    }
    *(short8*)(Wp + pk) = v;

    if (half == 0 && akg == 0) {                       // one thread per pair row
        float g0, g1, g2, g3;
        compute_gates(alpha, g0, g1, g2, g3);
        float w2e = (j == k) ? w2[j] : w2[64 + 63 * j - (j * (j - 1)) / 2 + (k - j - 1)];
        float2 ev;
        ev.x = g2 * w2e;
        ev.y = __uint_as_float(((unsigned)j << 8) | (unsigned)k);
        et[row] = ev;
    }
}

// ---------- poly: fused GEMM(X@W^T) epilogue + f1 + sigmoid ----------
// 256 blocks x 1024 thr (16 waves); block owns 32 samples; wave wv walks tiles wv, wv+16, ...
__global__ __launch_bounds__(1024) void poly_mfma(
    const float* __restrict__ X,
    const float* __restrict__ w0,
    const float* __restrict__ w1,
    const float* __restrict__ alpha,
    const short* __restrict__ Wp,
    const float2* __restrict__ et,
    float* __restrict__ out)
{
    __shared__ float xs[DD][36];     // transposed tile: xs[dim][sample]
    __shared__ float red[16][32];
    __shared__ float f1s[32];

    const int tid = threadIdx.x;
    const int lane = tid & 63, wv = tid >> 6;
    const int s0 = blockIdx.x * 32;

    for (int idx = tid; idx < 32 * 64; idx += 1024) {
        xs[idx & 63][idx >> 6] = X[(size_t)s0 * 64 + idx];
    }

    float g0, g1, g2, g3;
    compute_gates(alpha, g0, g1, g2, g3);

    // A fragments straight from global X (L1/L2-warm), converted in-register
    const int arow = lane & 15, akg = lane >> 4;
    const float* xr0 = X + (size_t)(s0 + arow) * 64 + 8 * akg;
    const float* xr1 = X + (size_t)(s0 + 16 + arow) * 64 + 8 * akg;
    short8 a0m0, a1m0, a0m1, a1m1;
    {
        f32x4 p0 = *(const f32x4*)(xr0);
        f32x4 p1 = *(const f32x4*)(xr0 + 4);
        f32x4 q0 = *(const f32x4*)(xr0 + 32);
        f32x4 q1 = *(const f32x4*)(xr0 + 36);
        f32x4 r0 = *(const f32x4*)(xr1);
        f32x4 r1 = *(const f32x4*)(xr1 + 4);
        f32x4 s0v = *(const f32x4*)(xr1 + 32);
        f32x4 s1v = *(const f32x4*)(xr1 + 36);
        #pragma unroll
        for (int e = 0; e < 4; ++e) {
            a0m0[e] = f2bf(p0[e]); a0m0[4 + e] = f2bf(p1[e]);
            a1m0[e] = f2bf(q0[e]); a1m0[4 + e] = f2bf(q1[e]);
            a0m1[e] = f2bf(r0[e]); a0m1[4 + e] = f2bf(r1[e]);
            a1m1[e] = f2bf(s0v[e]); a1m1[4 + e] = f2bf(s1v[e]);
        }
    }

    __syncthreads();

    float part0[4] = {0, 0, 0, 0}, part1[4] = {0, 0, 0, 0};

    // branchless 2-deep prefetch: dummy tile 130 is zeros, never consumed
    int nt = wv;
    int iA = (nt < NTILES) ? nt : NTILES;
    int iB = (nt + 16 < NTILES) ? nt + 16 : NTILES;
    const short* wbA = Wp + iA * 1024 + lane * 8;
    short8 bA0 = *(const short8*)wbA;
    short8 bA1 = *(const short8*)(wbA + 512);
    float2 eA = et[iA * 16 + arow];
    const short* wbB = Wp + iB * 1024 + lane * 8;
    short8 bB0 = *(const short8*)wbB;
    short8 bB1 = *(const short8*)(wbB + 512);
    float2 eB = et[iB * 16 + arow];

    while (nt < NTILES) {
        const int iC = (nt + 32 < NTILES) ? nt + 32 : NTILES;
        const short* wbC = Wp + iC * 1024 + lane * 8;
        short8 bC0 = *(const short8*)wbC;
        short8 bC1 = *(const short8*)(wbC + 512);
        float2 eC = et[iC * 16 + arow];

        f32x4 c0 = {0, 0, 0, 0}, c1 = {0, 0, 0, 0};
        c0 = __builtin_amdgcn_mfma_f32_16x16x32_bf16(a0m0, bA0, c0, 0, 0, 0);
        c0 = __builtin_amdgcn_mfma_f32_16x16x32_bf16(a1m0, bA1, c0, 0, 0, 0);
        c1 = __builtin_amdgcn_mfma_f32_16x16x32_bf16(a0m1, bA0, c1, 0, 0, 0);
        c1 = __builtin_amdgcn_mfma_f32_16x16x32_bf16(a1m1, bA1, c1, 0, 0, 0);

        const unsigned jk = __float_as_uint(eA.y);
        const int pj = jk >> 8, pk2 = jk & 255;
        const float bp = eA.x;
        const f32x4 xj0 = *(const f32x4*)&xs[pj][4 * akg];
        const f32x4 xk0 = *(const f32x4*)&xs[pk2][4 * akg];
        const f32x4 xj1 = *(const f32x4*)&xs[pj][16 + 4 * akg];
        const f32x4 xk1 = *(const f32x4*)&xs[pk2][16 + 4 * akg];
        #pragma unroll
        for (int r = 0; r < 4; ++r) {
            float t0 = fmaf(g3, c0[r], bp);
            part0[r] = fmaf(t0, xj0[r] * xk0[r], part0[r]);
            float t1 = fmaf(g3, c1[r], bp);
            part1[r] = fmaf(t1, xj1[r] * xk1[r], part1[r]);
        }
        bA0 = bB0; bA1 = bB1; eA = eB;
        bB0 = bC0; bB1 = bC1; eB = eC;
        nt += 16;
    }

    // reduce across the 16 pair-columns (lane bits 0..3)
    #pragma unroll
    for (int r = 0; r < 4; ++r) {
        float v0 = part0[r], v1 = part1[r];
        for (int m = 1; m <= 8; m <<= 1) {
            v0 += __shfl_xor(v0, m, 64);
            v1 += __shfl_xor(v1, m, 64);
        }
        part0[r] = v0; part1[r] = v1;
    }
    if ((lane & 15) == 0) {
        const int rb = 4 * (lane >> 4);
        #pragma unroll
        for (int r = 0; r < 4; ++r) {
            red[wv][rb + r] = part0[r];
            red[wv][16 + rb + r] = part1[r];
        }
    }

    // f1 (linear term): 32 threads per sample, 2 iters each
    {
        const int s = tid >> 5, u = tid & 31;
        float f1 = fmaf(w1[u], xs[u][s], w1[u + 32] * xs[u + 32][s]);
        for (int m = 1; m <= 16; m <<= 1) f1 += __shfl_xor(f1, m, 64);
        if (u == 0) f1s[s] = f1;
    }
    __syncthreads();

    if (tid < 32) {
        float s = 0.0f;
        #pragma unroll
        for (int w = 0; w < 16; ++w) s += red[w][tid];
        float f = fmaf(g0, w0[0], fmaf(g1, f1s[tid], s));
        out[s0 + tid] = 1.0f / (1.0f + __expf(-f));
    }
}

extern "C" void kernel_launch(void* const* d_in, const int* in_sizes, int n_in,
                              void* d_out, int out_size, void* d_ws, size_t ws_size,
                              hipStream_t stream)
{
    const float* X     = (const float*)d_in[0];
    const float* w0    = (const float*)d_in[1];
    const float* w1    = (const float*)d_in[2];
    const float* w2    = (const float*)d_in[3];
    const float* w3    = (const float*)d_in[4];
    const float* alpha = (const float*)d_in[5];
    float* out = (float*)d_out;

    char* ws = (char*)d_ws;
    short* Wp  = (short*)(ws + W_OFF);
    float2* et = (float2*)(ws + E_OFF);

    const int N = in_sizes[0] / DD;          // 8192

    build_kernel<<<(PTILES * 128 + 255) / 256, 256, 0, stream>>>(w2, w3, alpha, Wp, et);
    poly_mfma<<<N / 32, 1024, 0, stream>>>(X, w0, w1, alpha, Wp, et, out);
}